// Round 7
// baseline (186.595 us; speedup 1.0000x reference)
//
#include <hip/hip_runtime.h>

// Layout facts (floats):
//   input  x: (2,4,4,4,1048576)  -> slice(b,i) base = b*67108864 + i*16777216
//   output  : (2, 4*262144, 64)  -> slice(b,i) base = b*67108864 + i*16777216
// float4 strides: batch 16777216, level 4194304.
//
// Tables PRE-PERMUTED in bcast lane order:
//   d1p per batch: [zq:16][yh4:16][xh4:16][xl:4][yl:4] float4s, f4 = 4 z-subvals
//   p2  per batch: 4 partial tables [g:4][xp:16][yp:16][zp:16] floats
//   p3  per batch: [xp:4][G:256][c:16] floats
// Two dispatches:
//   D1 k_reduce: l1/l2/l3 reductions, 64KB pure-read blocks (3072 x 2)
//   D2 k_write : perm(4096) -> bcastL1(2048) -> bcastL2(2048, inline p2-sum)
//                -> bcastL3(512 x 128KB, inline p3 block-reduce); soft phasing
//                via block ordering, no hard drain between perm and bcast.

typedef float f4 __attribute__((ext_vector_type(4)));

__global__ __launch_bounds__(256) void k_reduce(const float* __restrict__ in,
                                                float* __restrict__ d1,
                                                float* __restrict__ p2,
                                                float* __restrict__ p3) {
    const int b = blockIdx.y;
    const int bx = blockIdx.x;
    const int tid = threadIdx.x;
    __shared__ float red[64];
    const f4* in4 = (const f4*)in;

    if (bx < 1024) {
        // ---- level 1 reduce: block per tlow = y'*16 + z'/4, 64KB read ----
        const int tlow = bx;
        const long base4 = (long)b * 16777216 + 4194304;
        float acc[4] = {0.f, 0.f, 0.f, 0.f};
        for (int dz = 0; dz < 4; ++dz) {
            long rb = base4 + (long)(dz * 1024 + tlow) * 1024;
#pragma unroll
            for (int k = 0; k < 4; ++k) {
                f4 v = __builtin_nontemporal_load(&in4[rb + k * 256 + tid]);
                acc[k] += v.x + v.y + v.z + v.w;
            }
        }
#pragma unroll
        for (int k = 0; k < 4; ++k) {        // reduce dx bits (tid 2..3)
            acc[k] += __shfl_xor(acc[k], 4);
            acc[k] += __shfl_xor(acc[k], 8);
        }
        if ((tid & 12) == 0) {
            int yp = tlow >> 4;
            int zp = ((tlow & 15) << 2) + (tid & 3);
#pragma unroll
            for (int k = 0; k < 4; ++k) {
                int xp = k * 16 + (tid >> 4);
                int f4i = (zp >> 2) * 4096 + (yp >> 2) * 256 +
                          (xp >> 2) * 16 + (xp & 3) * 4 + (yp & 3);
                d1[b * 262144 + f4i * 4 + (zp & 3)] = acc[k] * (1.0f / 64.0f);
            }
        }
    } else if (bx < 2048) {
        // ---- level 2 reduce partials: 4 dz per block (64KB) ----
        const int blk = bx - 1024;
        const int g = blk & 3, cell = blk >> 2;
        const int yp = cell >> 4, xp = cell & 15;
        const long base4 = (long)b * 16777216 + 2 * 4194304 + yp * 16384 + xp * 1024;
        float acc = 0.f;
        for (int dzi = 0; dzi < 4; ++dzi) {
            long rb = base4 + (long)(g * 4 + dzi) * 262144;
#pragma unroll
            for (int k = 0; k < 4; ++k) {
                f4 v = __builtin_nontemporal_load(&in4[rb + k * 256 + tid]);
                acc += v.x + v.y + v.z + v.w;   // z' = (tid>>2)&15
            }
        }
        acc += __shfl_xor(acc, 1);
        acc += __shfl_xor(acc, 2);
        if ((tid & 3) == 0) red[tid >> 2] = acc;
        __syncthreads();
        if (tid < 16) {
            float s = red[tid] + red[16 + tid] + red[32 + tid] + red[48 + tid];
            p2[(b * 4 + g) * 4096 + xp * 256 + yp * 16 + tid] = s;
        }
    } else {
        // ---- level 3 reduce partials: 16 k-chunks per block (64KB) ----
        const int blk = bx - 2048;
        const int kc = blk & 3;
        const int orig = blk >> 2;           // x'(2b) hi(4b) dxg(2b)
        const int xp = orig >> 6, hi = (orig >> 2) & 15, dxg = orig & 3;
        const long base4 = (long)b * 16777216 + 3 * 4194304 +
                           (long)hi * 262144 + xp * 65536 + dxg * 16384;
        float acc = 0.f;                     // c = tid>>4 fixed per thread
        for (int kk = 0; kk < 16; ++kk) {
            f4 v = __builtin_nontemporal_load(&in4[base4 + (kc * 16 + kk) * 256 + tid]);
            acc += v.x + v.y + v.z + v.w;
        }
        acc += __shfl_xor(acc, 1);
        acc += __shfl_xor(acc, 2);
        acc += __shfl_xor(acc, 4);
        acc += __shfl_xor(acc, 8);
        if ((tid & 15) == 0) red[tid >> 4] = acc;
        __syncthreads();
        if (tid < 16) {
            int G = (hi * 4 + dxg) * 4 + kc;             // 0..255
            p3[((b * 4 + xp) * 256 + G) * 16 + tid] = red[tid];
        }
    }
}

__global__ __launch_bounds__(256) void k_write(const float* __restrict__ in,
                                               const float* __restrict__ d1,
                                               const float* __restrict__ p2,
                                               const float* __restrict__ p3,
                                               float* __restrict__ out) {
    const int b = blockIdx.y;
    const int bx = blockIdx.x;
    const int tid = threadIdx.x;
    __shared__ f4 smem4[1040];               // 16.6 KB, shared across paths
    f4* out4 = (f4*)out;

    if (bx < 4096) {
        // ---- level 0: pure permutation via LDS tile ----
        float* smem = (float*)smem4;
        const f4* in4 = (const f4*)in;
        const int Y_hi = bx >> 6, Z_hi = bx & 63;
        const long in_b4 = (long)b * 16777216;
#pragma unroll
        for (int k = 0; k < 4; ++k) {
            int idx = k * 256 + tid;
            int r = idx >> 6, col4 = idx & 63;
            int Y = Y_hi * 4 + (r >> 2), Z = Z_hi * 4 + (r & 3);
            f4 v = __builtin_nontemporal_load(&in4[in_b4 + (long)Y * 16384 + Z * 64 + col4]);
            *(f4*)&smem[r * 260 + col4 * 4] = v;
        }
        __syncthreads();
        const long out_b4 = (long)b * 16777216 + (long)Z_hi * 65536 + Y_hi * 1024;
#pragma unroll
        for (int k = 0; k < 4; ++k) {
            int idx = k * 256 + tid;
            int X = ((idx >> 4) << 2) + ((tid >> 2) & 3);
            int row0 = (tid & 3) * 4;
            f4 v;
            v.x = smem[(row0 + 0) * 260 + X];
            v.y = smem[(row0 + 1) * 260 + X];
            v.z = smem[(row0 + 2) * 260 + X];
            v.w = smem[(row0 + 3) * 260 + X];
            __builtin_nontemporal_store(v, &out4[out_b4 + idx]);
        }
    } else if (bx < 6144) {
        // ---- level 1 broadcast: two coalesced 4KB d1 rows per block ----
        const int blk = bx - 4096;
        const f4* d14 = (const f4*)d1;
        const int bx0 = blk * 2;
        const int base = b * 65536 + ((bx0 >> 6) & 15) * 4096 + (bx0 & 15) * 256 + tid;
        const f4 v0 = d14[base];
        const f4 v1 = d14[base + 256];
        const long ob = (long)b * 16777216 + 4194304 + (long)blk * 2048;
#pragma unroll
        for (int j = 0; j < 8; ++j)
            __builtin_nontemporal_store((j < 4) ? v0 : v1, &out4[ob + j * 256 + tid]);
    } else if (bx < 8192) {
        // ---- level 2 broadcast, inline 4-way p2 combine (L2-resident) ----
        const int blk = bx - 6144;
        const f4* p24 = (const f4*)p2;
        const int bx0 = blk * 2;
        const int t6 = tid & 63;
        const int xp = ((t6 >> 4) << 2) + ((t6 >> 2) & 3);   // xh2*4 + xl
        const int ylo = t6 & 3;
        f4 v01[2];
#pragma unroll
        for (int r = 0; r < 2; ++r) {
            int row = bx0 + r;
            int zq = (row >> 6) & 3, yq = row & 3;
            int yp = yq * 4 + ylo;
            f4 s = {0.f, 0.f, 0.f, 0.f};
#pragma unroll
            for (int g = 0; g < 4; ++g)
                s += p24[(b * 4 + g) * 1024 + xp * 64 + yp * 4 + zq];
            v01[r] = s * (1.0f / 4096.0f);
        }
        const long ob = (long)b * 16777216 + 2 * 4194304 + (long)blk * 2048;
#pragma unroll
        for (int j = 0; j < 8; ++j)
            __builtin_nontemporal_store((j < 4) ? v01[0] : v01[1],
                                        &out4[ob + j * 256 + tid]);
    } else {
        // ---- level 3 broadcast: inline block-reduce of p3 (64KB, L2) ----
        const int blk = bx - 8192;           // 0..511, 128KB output each
        const f4* p34 = (const f4*)p3;
        const int o = tid & 15, part = tid >> 4;       // o = xp*4 + cq
        const int xp = o >> 2, cq = o & 3;
        f4 s = {0.f, 0.f, 0.f, 0.f};
#pragma unroll
        for (int j = 0; j < 16; ++j) {
            int G = part * 16 + j;
            s += p34[((b * 4 + xp) * 256 + G) * 4 + cq];
        }
        f4* red = smem4;                     // [part:16][o:16]
        red[part * 16 + o] = s;
        __syncthreads();
        f4* tab = smem4 + 256;
        if (tid < 16) {
            f4 t = {0.f, 0.f, 0.f, 0.f};
#pragma unroll
            for (int g = 0; g < 16; ++g) t += red[g * 16 + tid];
            tab[tid] = t * (1.0f / 262144.0f);
        }
        __syncthreads();
        const f4 v = tab[tid & 15];
        const long ob = (long)b * 16777216 + 3 * 4194304 + (long)blk * 8192;
#pragma unroll
        for (int j = 0; j < 32; ++j)
            __builtin_nontemporal_store(v, &out4[ob + j * 256 + tid]);
    }
}

extern "C" void kernel_launch(void* const* d_in, const int* in_sizes, int n_in,
                              void* d_out, int out_size, void* d_ws, size_t ws_size,
                              hipStream_t stream) {
    const float* in = (const float*)d_in[0];
    float* out = (float*)d_out;
    float* ws = (float*)d_ws;
    float* d1 = ws;                               // 2*262144 = 524288 floats
    float* p2 = ws + 524288;                      // 2*4*4096 = 32768
    float* p3 = ws + 524288 + 65536;              // 2*4*256*16 = 32768
    k_reduce<<<dim3(3072, 2), 256, 0, stream>>>(in, d1, p2, p3);
    k_write <<<dim3(8704, 2), 256, 0, stream>>>(in, d1, p2, p3, out);
}

// Round 8
// 181.943 us; speedup vs baseline: 1.0256x; 1.0256x over previous
//
#include <hip/hip_runtime.h>

// Layout facts (floats):
//   input  x: (2,4,4,4,1048576)  -> slice(b,i) base = b*67108864 + i*16777216
//   output  : (2, 4*262144, 64)  -> slice(b,i) base = b*67108864 + i*16777216
// float4 strides: batch 16777216, level 4194304.
//
// Tables PRE-PERMUTED in bcast lane order:
//   d1p per batch: [zq:16][yh4:16][xh4:16][xl:4][yl:4] float4s, f4 = 4 z-subvals
//   p2  per batch: 4 partial tables [g:4][xp:16][yp:16][zp:16] floats
//   p3  per batch: [xp:4][G:256][c:16] floats
// Two dispatches, LPT-ordered blocks (longest first, no ragged tail):
//   D1 k_read : reduce blocks (6144 x 64KB pure-read) FIRST, then perm (8192).
//   D2 k_bcast: l3 blocks (1024 x 128KB, inline p3 reduce) FIRST, then
//               l1 (d1 rows) and l2 (inline p2 sum) at uniform 32KB.

typedef float f4 __attribute__((ext_vector_type(4)));

__global__ __launch_bounds__(256) void k_read(const float* __restrict__ in,
                                              float* __restrict__ out,
                                              float* __restrict__ d1,
                                              float* __restrict__ p2,
                                              float* __restrict__ p3) {
    const int bx = blockIdx.x;
    const int tid = threadIdx.x;
    __shared__ float smem[16 * 260];
    const f4* in4 = (const f4*)in;

    if (bx < 6144) {
        // ================= reductions (64KB pure-read blocks) =================
        const int b = bx & 1;
        const int rbx = bx >> 1;             // 0..3071
        float* red = smem;

        if (rbx < 1024) {
            // ---- level 1 reduce: block per tlow = y'*16 + z'/4 ----
            const int tlow = rbx;
            const long base4 = (long)b * 16777216 + 4194304;
            float acc[4] = {0.f, 0.f, 0.f, 0.f};
            for (int dz = 0; dz < 4; ++dz) {
                long rb = base4 + (long)(dz * 1024 + tlow) * 1024;
#pragma unroll
                for (int k = 0; k < 4; ++k) {
                    f4 v = __builtin_nontemporal_load(&in4[rb + k * 256 + tid]);
                    acc[k] += v.x + v.y + v.z + v.w;
                }
            }
#pragma unroll
            for (int k = 0; k < 4; ++k) {    // reduce dx bits (tid 2..3)
                acc[k] += __shfl_xor(acc[k], 4);
                acc[k] += __shfl_xor(acc[k], 8);
            }
            if ((tid & 12) == 0) {
                int yp = tlow >> 4;
                int zp = ((tlow & 15) << 2) + (tid & 3);
#pragma unroll
                for (int k = 0; k < 4; ++k) {
                    int xp = k * 16 + (tid >> 4);
                    int f4i = (zp >> 2) * 4096 + (yp >> 2) * 256 +
                              (xp >> 2) * 16 + (xp & 3) * 4 + (yp & 3);
                    d1[b * 262144 + f4i * 4 + (zp & 3)] = acc[k] * (1.0f / 64.0f);
                }
            }
        } else if (rbx < 2048) {
            // ---- level 2 reduce partials: 4 dz per block ----
            const int blk = rbx - 1024;
            const int g = blk & 3, cell = blk >> 2;
            const int yp = cell >> 4, xp = cell & 15;
            const long base4 = (long)b * 16777216 + 2 * 4194304 + yp * 16384 + xp * 1024;
            float acc = 0.f;
            for (int dzi = 0; dzi < 4; ++dzi) {
                long rb = base4 + (long)(g * 4 + dzi) * 262144;
#pragma unroll
                for (int k = 0; k < 4; ++k) {
                    f4 v = __builtin_nontemporal_load(&in4[rb + k * 256 + tid]);
                    acc += v.x + v.y + v.z + v.w;   // z' = (tid>>2)&15
                }
            }
            acc += __shfl_xor(acc, 1);
            acc += __shfl_xor(acc, 2);
            if ((tid & 3) == 0) red[tid >> 2] = acc;
            __syncthreads();
            if (tid < 16) {
                float s = red[tid] + red[16 + tid] + red[32 + tid] + red[48 + tid];
                p2[(b * 4 + g) * 4096 + xp * 256 + yp * 16 + tid] = s;
            }
        } else {
            // ---- level 3 reduce partials: 16 k-chunks per block ----
            const int blk = rbx - 2048;
            const int kc = blk & 3;
            const int orig = blk >> 2;       // x'(2b) hi(4b) dxg(2b)
            const int xp = orig >> 6, hi = (orig >> 2) & 15, dxg = orig & 3;
            const long base4 = (long)b * 16777216 + 3 * 4194304 +
                               (long)hi * 262144 + xp * 65536 + dxg * 16384;
            float acc = 0.f;                 // c = tid>>4 fixed per thread
            for (int kk = 0; kk < 16; ++kk) {
                f4 v = __builtin_nontemporal_load(&in4[base4 + (kc * 16 + kk) * 256 + tid]);
                acc += v.x + v.y + v.z + v.w;
            }
            acc += __shfl_xor(acc, 1);
            acc += __shfl_xor(acc, 2);
            acc += __shfl_xor(acc, 4);
            acc += __shfl_xor(acc, 8);
            if ((tid & 15) == 0) red[tid >> 4] = acc;
            __syncthreads();
            if (tid < 16) {
                int G = (hi * 4 + dxg) * 4 + kc;         // 0..255
                p3[((b * 4 + xp) * 256 + G) * 16 + tid] = red[tid];
            }
        }
    } else {
        // ================= level 0 permutation via LDS tile =================
        const int p = bx - 6144;             // 0..8191
        const int b = p >> 12;
        const int rem = p & 4095;
        const int Y_hi = rem >> 6, Z_hi = rem & 63;
        f4* out4 = (f4*)out;
        const long in_b4 = (long)b * 16777216;
#pragma unroll
        for (int k = 0; k < 4; ++k) {
            int idx = k * 256 + tid;
            int r = idx >> 6, col4 = idx & 63;
            int Y = Y_hi * 4 + (r >> 2), Z = Z_hi * 4 + (r & 3);
            f4 v = __builtin_nontemporal_load(&in4[in_b4 + (long)Y * 16384 + Z * 64 + col4]);
            *(f4*)&smem[r * 260 + col4 * 4] = v;
        }
        __syncthreads();
        const long out_b4 = (long)b * 16777216 + (long)Z_hi * 65536 + Y_hi * 1024;
#pragma unroll
        for (int k = 0; k < 4; ++k) {
            int idx = k * 256 + tid;
            int X = ((idx >> 4) << 2) + ((tid >> 2) & 3);
            int row0 = (tid & 3) * 4;
            f4 v;
            v.x = smem[(row0 + 0) * 260 + X];
            v.y = smem[(row0 + 1) * 260 + X];
            v.z = smem[(row0 + 2) * 260 + X];
            v.w = smem[(row0 + 3) * 260 + X];
            __builtin_nontemporal_store(v, &out4[out_b4 + idx]);
        }
    }
}

__global__ __launch_bounds__(256) void k_bcast(const float* __restrict__ d1,
                                               const float* __restrict__ p2,
                                               const float* __restrict__ p3,
                                               float* __restrict__ out) {
    const int b = blockIdx.y;
    const int bx = blockIdx.x;
    const int tid = threadIdx.x;
    __shared__ f4 smem4[280];
    f4* out4 = (f4*)out;

    if (bx < 512) {
        // ---- level 3 (FIRST, longest): inline p3 block-reduce + 128KB out ----
        const int blk = bx;                  // 0..511
        const f4* p34 = (const f4*)p3;
        const int o = tid & 15, part = tid >> 4;       // o = xp*4 + cq
        const int xp = o >> 2, cq = o & 3;
        f4 s = {0.f, 0.f, 0.f, 0.f};
#pragma unroll
        for (int j = 0; j < 16; ++j) {
            int G = part * 16 + j;
            s += p34[((b * 4 + xp) * 256 + G) * 4 + cq];
        }
        f4* red = smem4;                     // [part:16][o:16]
        red[part * 16 + o] = s;
        __syncthreads();
        f4* tab = smem4 + 256;
        if (tid < 16) {
            f4 t = {0.f, 0.f, 0.f, 0.f};
#pragma unroll
            for (int g = 0; g < 16; ++g) t += red[g * 16 + tid];
            tab[tid] = t * (1.0f / 262144.0f);
        }
        __syncthreads();
        const f4 v = tab[tid & 15];
        const long ob = (long)b * 16777216 + 3 * 4194304 + (long)blk * 8192;
#pragma unroll
        for (int j = 0; j < 32; ++j)
            __builtin_nontemporal_store(v, &out4[ob + j * 256 + tid]);
    } else if (bx < 2560) {
        // ---- level 1 broadcast: two coalesced 4KB d1 rows per block ----
        const int blk = bx - 512;
        const f4* d14 = (const f4*)d1;
        const int bx0 = blk * 2;
        const int base = b * 65536 + ((bx0 >> 6) & 15) * 4096 + (bx0 & 15) * 256 + tid;
        const f4 v0 = d14[base];
        const f4 v1 = d14[base + 256];
        const long ob = (long)b * 16777216 + 4194304 + (long)blk * 2048;
#pragma unroll
        for (int j = 0; j < 8; ++j)
            __builtin_nontemporal_store((j < 4) ? v0 : v1, &out4[ob + j * 256 + tid]);
    } else {
        // ---- level 2 broadcast, inline 4-way p2 combine (L2-resident) ----
        const int blk = bx - 2560;
        const f4* p24 = (const f4*)p2;
        const int bx0 = blk * 2;
        const int t6 = tid & 63;
        const int xp = ((t6 >> 4) << 2) + ((t6 >> 2) & 3);   // xh2*4 + xl
        const int ylo = t6 & 3;
        f4 v01[2];
#pragma unroll
        for (int r = 0; r < 2; ++r) {
            int row = bx0 + r;
            int zq = (row >> 6) & 3, yq = row & 3;
            int yp = yq * 4 + ylo;
            f4 s = {0.f, 0.f, 0.f, 0.f};
#pragma unroll
            for (int g = 0; g < 4; ++g)
                s += p24[(b * 4 + g) * 1024 + xp * 64 + yp * 4 + zq];
            v01[r] = s * (1.0f / 4096.0f);
        }
        const long ob = (long)b * 16777216 + 2 * 4194304 + (long)blk * 2048;
#pragma unroll
        for (int j = 0; j < 8; ++j)
            __builtin_nontemporal_store((j < 4) ? v01[0] : v01[1],
                                        &out4[ob + j * 256 + tid]);
    }
}

extern "C" void kernel_launch(void* const* d_in, const int* in_sizes, int n_in,
                              void* d_out, int out_size, void* d_ws, size_t ws_size,
                              hipStream_t stream) {
    const float* in = (const float*)d_in[0];
    float* out = (float*)d_out;
    float* ws = (float*)d_ws;
    float* d1 = ws;                               // 2*262144 = 524288 floats
    float* p2 = ws + 524288;                      // 2*4*4096 = 32768
    float* p3 = ws + 524288 + 65536;              // 2*4*256*16 = 32768
    k_read <<<dim3(14336),   256, 0, stream>>>(in, out, d1, p2, p3);
    k_bcast<<<dim3(4608, 2), 256, 0, stream>>>(d1, p2, p3, out);
}